// Round 6
// baseline (6071.107 us; speedup 1.0000x reference)
//
#include <hip/hip_runtime.h>

#define NN 50000
#define EE 800000

__device__ __forceinline__ float leaky(float z) { return z >= 0.f ? z : 0.01f * z; }

// ---------------------------------------------------------------------------
// Fused node GEMM: q,k,v = x@W*+b*, h = x@Ws+bs (the skip term, scattered into
// later). Block = 256 threads = 4 col-slots x 64 cols; each slot handles ROWS
// rows -> 32 rows/block. Weights re-read per block but L1/L2 resident.
// ---------------------------------------------------------------------------
template <int ROWS>
__global__ __launch_bounds__(256) void qkvs_k(
    const float* __restrict__ X,
    const float* __restrict__ Wq, const float* __restrict__ bq,
    const float* __restrict__ Wk, const float* __restrict__ bk,
    const float* __restrict__ Wv, const float* __restrict__ bv,
    const float* __restrict__ Ws, const float* __restrict__ bs,
    float* __restrict__ q, float* __restrict__ k, float* __restrict__ v,
    float* __restrict__ h)
{
    constexpr int RPB = 4 * ROWS;
    __shared__ float sX[RPB * 64];
    int base = blockIdx.x * RPB;
    for (int i = threadIdx.x; i < RPB * 64; i += 256) {
        int r = base + (i >> 6);
        sX[i] = (r < NN) ? X[r * 64 + (i & 63)] : 0.f;
    }
    __syncthreads();
    int col = threadIdx.x & 63;
    int slot = threadIdx.x >> 6;
    float accq[ROWS], acck[ROWS], accv[ROWS], accs[ROWS];
#pragma unroll
    for (int r = 0; r < ROWS; ++r) {
        accq[r] = bq[col]; acck[r] = bk[col];
        accv[r] = bv[col]; accs[r] = bs[col];
    }
#pragma unroll 16
    for (int kk = 0; kk < 64; ++kk) {
        float wq = Wq[kk * 64 + col], wk = Wk[kk * 64 + col];
        float wv = Wv[kk * 64 + col], ws = Ws[kk * 64 + col];
#pragma unroll
        for (int r = 0; r < ROWS; ++r) {
            float xv = sX[(slot * ROWS + r) * 64 + kk];  // wave-uniform -> LDS broadcast
            accq[r] = fmaf(xv, wq, accq[r]);
            acck[r] = fmaf(xv, wk, acck[r]);
            accv[r] = fmaf(xv, wv, accv[r]);
            accs[r] = fmaf(xv, ws, accs[r]);
        }
    }
#pragma unroll
    for (int r = 0; r < ROWS; ++r) {
        int row = base + slot * ROWS + r;
        if (row < NN) {
            q[row * 64 + col] = accq[r];
            k[row * 64 + col] = acck[r];
            v[row * 64 + col] = accv[r];
            h[row * 64 + col] = accs[r];
        }
    }
}

// ---------------------------------------------------------------------------
// Generic small linear for the MLP head.
// ---------------------------------------------------------------------------
template <int FI, int FO, int ACT>
__global__ void linear_k(const float* __restrict__ X, const float* __restrict__ W,
                         const float* __restrict__ b, float* __restrict__ Y, int n)
{
    int idx = blockIdx.x * blockDim.x + threadIdx.x;
    if (idx >= n * FO) return;
    int col = idx % FO, row = idx / FO;
    float acc = b[col];
    const float* xr = X + row * FI;
#pragma unroll
    for (int kk = 0; kk < FI; ++kk) acc = fmaf(xr[kk], W[kk * FO + col], acc);
    if (ACT) acc = leaky(acc);
    Y[idx] = acc;
}

__global__ void leaky_k(float* __restrict__ Y, int n)
{
    int i = blockIdx.x * blockDim.x + threadIdx.x;
    if (i < n) Y[i] = leaky(Y[i]);
}

// monotone float->uint encoding for atomicMax on signed floats
__device__ __forceinline__ unsigned int enc_f(float f)
{
    unsigned int b = __float_as_uint(f);
    return (b & 0x80000000u) ? ~b : (b | 0x80000000u);
}
__device__ __forceinline__ float dec_f(unsigned int e)
{
    return __uint_as_float((e & 0x80000000u) ? (e ^ 0x80000000u) : ~e);
}

// ---------------------------------------------------------------------------
// Edge pass A: alpha[e,h] = <q[dst,h,:], k[src,h,:] + (ea[e]@We)[h,:]> / sqrt(32)
// e-projection recomputed from LDS-staged We (16x64). One thread per (edge,head).
// ---------------------------------------------------------------------------
__global__ __launch_bounds__(256) void edge_alpha_k(
    const int* __restrict__ ei, const float* __restrict__ ea,
    const float* __restrict__ q, const float* __restrict__ k,
    const float* __restrict__ We, float* __restrict__ alpha,
    unsigned int* __restrict__ amax)
{
    __shared__ float sWe[16 * 64];
    for (int i = threadIdx.x; i < 16 * 64; i += 256) sWe[i] = We[i];
    __syncthreads();
    int t = blockIdx.x * 256 + threadIdx.x;
    if (t >= EE * 2) return;
    int e = t >> 1, h = t & 1;
    int src = ei[e], dst = ei[EE + e];

    float av[16];
    const float4* a4 = (const float4*)(ea + e * 16);
#pragma unroll
    for (int i = 0; i < 4; ++i) {
        float4 f = a4[i];
        av[i * 4 + 0] = f.x; av[i * 4 + 1] = f.y; av[i * 4 + 2] = f.z; av[i * 4 + 3] = f.w;
    }
    float qv[32], kv[32];
    const float4* q4 = (const float4*)(q + dst * 64 + h * 32);
    const float4* k4 = (const float4*)(k + src * 64 + h * 32);
#pragma unroll
    for (int i = 0; i < 8; ++i) {
        float4 fq = q4[i], fk = k4[i];
        qv[i * 4 + 0] = fq.x; qv[i * 4 + 1] = fq.y; qv[i * 4 + 2] = fq.z; qv[i * 4 + 3] = fq.w;
        kv[i * 4 + 0] = fk.x; kv[i * 4 + 1] = fk.y; kv[i * 4 + 2] = fk.z; kv[i * 4 + 3] = fk.w;
    }
    float acc = 0.f;
#pragma unroll
    for (int c = 0; c < 32; ++c) {
        float ev = 0.f;
#pragma unroll
        for (int i = 0; i < 16; ++i) ev = fmaf(av[i], sWe[i * 64 + h * 32 + c], ev);
        acc = fmaf(qv[c], kv[c] + ev, acc);
    }
    acc *= 0.17677669529663687f;  // 1/sqrt(32)
    alpha[t] = acc;
    atomicMax(amax + dst * 2 + h, enc_f(acc));
}

// ---------------------------------------------------------------------------
// Edge pass B: ex = exp(alpha - amax[dst]); denom[dst] += ex (segment sum)
// ---------------------------------------------------------------------------
__global__ void edge_softmax_k(const int* __restrict__ ei, float* __restrict__ alpha,
                               const unsigned int* __restrict__ amax,
                               float* __restrict__ denom)
{
    int t = blockIdx.x * blockDim.x + threadIdx.x;
    if (t >= EE * 2) return;
    int e = t >> 1, h = t & 1;
    int dst = ei[EE + e];
    float m = dec_f(amax[dst * 2 + h]);
    float ex = expf(alpha[t] - m);
    alpha[t] = ex;
    atomicAdd(denom + dst * 2 + h, ex);
}

// ---------------------------------------------------------------------------
// Edge pass C: out[dst] += (v[src] + e) * ex/denom[dst]  (32 atomics/thread)
// ---------------------------------------------------------------------------
__global__ __launch_bounds__(256) void edge_msg_k(
    const int* __restrict__ ei, const float* __restrict__ ea,
    const float* __restrict__ v, const float* __restrict__ We,
    const float* __restrict__ alpha, const float* __restrict__ denom,
    float* __restrict__ out)
{
    __shared__ float sWe[16 * 64];
    for (int i = threadIdx.x; i < 16 * 64; i += 256) sWe[i] = We[i];
    __syncthreads();
    int t = blockIdx.x * 256 + threadIdx.x;
    if (t >= EE * 2) return;
    int e = t >> 1, h = t & 1;
    int src = ei[e], dst = ei[EE + e];
    float a = alpha[t] / (denom[dst * 2 + h] + 1e-16f);

    float av[16];
    const float4* a4 = (const float4*)(ea + e * 16);
#pragma unroll
    for (int i = 0; i < 4; ++i) {
        float4 f = a4[i];
        av[i * 4 + 0] = f.x; av[i * 4 + 1] = f.y; av[i * 4 + 2] = f.z; av[i * 4 + 3] = f.w;
    }
    float vv[32];
    const float4* v4 = (const float4*)(v + src * 64 + h * 32);
#pragma unroll
    for (int i = 0; i < 8; ++i) {
        float4 f = v4[i];
        vv[i * 4 + 0] = f.x; vv[i * 4 + 1] = f.y; vv[i * 4 + 2] = f.z; vv[i * 4 + 3] = f.w;
    }
    float* orow = out + dst * 64 + h * 32;
#pragma unroll
    for (int c = 0; c < 32; ++c) {
        float ev = 0.f;
#pragma unroll
        for (int i = 0; i < 16; ++i) ev = fmaf(av[i], sWe[i * 64 + h * 32 + c], ev);
        atomicAdd(orow + c, (vv[c] + ev) * a);
    }
}

// ---------------------------------------------------------------------------
extern "C" void kernel_launch(void* const* d_in, const int* in_sizes, int n_in,
                              void* d_out, int out_size, void* d_ws, size_t ws_size,
                              hipStream_t stream)
{
    const float* x = (const float*)d_in[0];
    const int* ei = (const int*)d_in[2];
    const float* ea = (const float*)d_in[3];
    const float* Wq[2] = {(const float*)d_in[5], (const float*)d_in[14]};
    const float* bq[2] = {(const float*)d_in[6], (const float*)d_in[15]};
    const float* Wk[2] = {(const float*)d_in[7], (const float*)d_in[16]};
    const float* bk[2] = {(const float*)d_in[8], (const float*)d_in[17]};
    const float* Wv[2] = {(const float*)d_in[9], (const float*)d_in[18]};
    const float* bv[2] = {(const float*)d_in[10], (const float*)d_in[19]};
    const float* We[2] = {(const float*)d_in[11], (const float*)d_in[20]};
    const float* Ws[2] = {(const float*)d_in[12], (const float*)d_in[21]};
    const float* bs[2] = {(const float*)d_in[13], (const float*)d_in[22]};
    const float* Wm1 = (const float*)d_in[23];
    const float* bm1 = (const float*)d_in[24];
    const float* Wm2 = (const float*)d_in[25];
    const float* bm2 = (const float*)d_in[26];

    float* ws = (float*)d_ws;
    float* q = ws;                    // N*64
    float* k = q + NN * 64;           // N*64
    float* v = k + NN * 64;           // N*64
    float* h1 = v + NN * 64;          // N*64
    float* h2 = h1 + NN * 64;         // N*64
    float* alpha = h2 + NN * 64;      // E*2
    unsigned int* amax = (unsigned int*)(alpha + EE * 2);  // N*2
    float* denom = (float*)(amax + NN * 2);                // N*2
    float* tmp = q;                   // N*32 — q is dead after the edge passes

    const float* xin = x;
    float* hout[2] = {h1, h2};
    int qkvs_grid = (NN + 31) / 32;
    int edge_grid = (EE * 2 + 255) / 256;

    for (int L = 0; L < 2; ++L) {
        float* h = hout[L];
        qkvs_k<8><<<qkvs_grid, 256, 0, stream>>>(
            xin, Wq[L], bq[L], Wk[L], bk[L], Wv[L], bv[L], Ws[L], bs[L], q, k, v, h);
        // zero amax (encoded -inf) and denom in one memset (contiguous)
        hipMemsetAsync(amax, 0, (size_t)NN * 4 * sizeof(float), stream);
        edge_alpha_k<<<edge_grid, 256, 0, stream>>>(ei, ea, q, k, We[L], alpha, amax);
        edge_softmax_k<<<edge_grid, 256, 0, stream>>>(ei, alpha, amax, denom);
        edge_msg_k<<<edge_grid, 256, 0, stream>>>(ei, ea, v, We[L], alpha, denom, h);
        leaky_k<<<(NN * 64 + 255) / 256, 256, 0, stream>>>(h, NN * 64);
        xin = h;
    }
    linear_k<64, 32, 1><<<(NN * 32 + 255) / 256, 256, 0, stream>>>(h2, Wm1, bm1, tmp, NN);
    linear_k<32, 32, 0><<<(NN * 32 + 255) / 256, 256, 0, stream>>>(tmp, Wm2, bm2, (float*)d_out, NN);
}

// Round 13
// 859.709 us; speedup vs baseline: 7.0618x; 7.0618x over previous
//
#include <hip/hip_runtime.h>

#define NN 50000
#define EE 800000

__device__ __forceinline__ float leaky(float z) { return z >= 0.f ? z : 0.01f * z; }

// ---------------------------------------------------------------------------
// Fused node GEMM: q,k,v = x@W*+b*, h = x@Ws+bs (skip term; attn adds into it).
// ---------------------------------------------------------------------------
template <int ROWS>
__global__ __launch_bounds__(256) void qkvs_k(
    const float* __restrict__ X,
    const float* __restrict__ Wq, const float* __restrict__ bq,
    const float* __restrict__ Wk, const float* __restrict__ bk,
    const float* __restrict__ Wv, const float* __restrict__ bv,
    const float* __restrict__ Ws, const float* __restrict__ bs,
    float* __restrict__ q, float* __restrict__ k, float* __restrict__ v,
    float* __restrict__ h)
{
    constexpr int RPB = 4 * ROWS;
    __shared__ float sX[RPB * 64];
    int base = blockIdx.x * RPB;
    for (int i = threadIdx.x; i < RPB * 64; i += 256) {
        int r = base + (i >> 6);
        sX[i] = (r < NN) ? X[r * 64 + (i & 63)] : 0.f;
    }
    __syncthreads();
    int col = threadIdx.x & 63;
    int slot = threadIdx.x >> 6;
    float accq[ROWS], acck[ROWS], accv[ROWS], accs[ROWS];
#pragma unroll
    for (int r = 0; r < ROWS; ++r) {
        accq[r] = bq[col]; acck[r] = bk[col];
        accv[r] = bv[col]; accs[r] = bs[col];
    }
#pragma unroll 16
    for (int kk = 0; kk < 64; ++kk) {
        float wq = Wq[kk * 64 + col], wk = Wk[kk * 64 + col];
        float wv = Wv[kk * 64 + col], ws = Ws[kk * 64 + col];
#pragma unroll
        for (int r = 0; r < ROWS; ++r) {
            float xv = sX[(slot * ROWS + r) * 64 + kk];
            accq[r] = fmaf(xv, wq, accq[r]);
            acck[r] = fmaf(xv, wk, acck[r]);
            accv[r] = fmaf(xv, wv, accv[r]);
            accs[r] = fmaf(xv, ws, accs[r]);
        }
    }
#pragma unroll
    for (int r = 0; r < ROWS; ++r) {
        int row = base + slot * ROWS + r;
        if (row < NN) {
            q[row * 64 + col] = accq[r];
            k[row * 64 + col] = acck[r];
            v[row * 64 + col] = accv[r];
            h[row * 64 + col] = accs[r];
        }
    }
}

// ---------------------------------------------------------------------------
// MLP linear
// ---------------------------------------------------------------------------
template <int FI, int FO, int ACT>
__global__ void linear_k(const float* __restrict__ X, const float* __restrict__ W,
                         const float* __restrict__ b, float* __restrict__ Y, int n)
{
    int idx = blockIdx.x * blockDim.x + threadIdx.x;
    if (idx >= n * FO) return;
    int col = idx % FO, row = idx / FO;
    float acc = b[col];
    const float* xr = X + row * FI;
#pragma unroll
    for (int kk = 0; kk < FI; ++kk) acc = fmaf(xr[kk], W[kk * FO + col], acc);
    if (ACT) acc = leaky(acc);
    Y[idx] = acc;
}

// ---------------------------------------------------------------------------
// CSR build (graph is identical for both layers -> build once per launch)
// ---------------------------------------------------------------------------
__global__ void hist_k(const int* __restrict__ ei, int* __restrict__ deg)
{
    int e = blockIdx.x * 256 + threadIdx.x;
    if (e < EE) atomicAdd(&deg[ei[EE + e]], 1);
}

// single-block scan over NN elements: rowptr (size NN+1) + fill (= exclusive)
__global__ __launch_bounds__(1024) void scan_k(const int* __restrict__ deg,
                                               int* __restrict__ rowptr,
                                               int* __restrict__ fill)
{
    __shared__ int sbuf[1024];
    __shared__ int carry;
    int tid = threadIdx.x;
    if (tid == 0) { carry = 0; rowptr[0] = 0; }
    __syncthreads();
    for (int base = 0; base < NN; base += 1024) {
        int i = base + tid;
        int x = (i < NN) ? deg[i] : 0;
        sbuf[tid] = x;
        __syncthreads();
#pragma unroll
        for (int off = 1; off < 1024; off <<= 1) {
            int t = (tid >= off) ? sbuf[tid - off] : 0;
            __syncthreads();
            sbuf[tid] += t;
            __syncthreads();
        }
        int incl = sbuf[tid];
        if (i < NN) {
            rowptr[i + 1] = carry + incl;
            fill[i] = carry + incl - x;   // exclusive prefix = write cursor
        }
        __syncthreads();
        if (tid == 0) carry += sbuf[1023];
        __syncthreads();
    }
}

__global__ void scatter_k(const int* __restrict__ ei, int* __restrict__ fill,
                          int* __restrict__ srcs, int* __restrict__ eids)
{
    int e = blockIdx.x * 256 + threadIdx.x;
    if (e < EE) {
        int dst = ei[EE + e];
        int pos = atomicAdd(&fill[dst], 1);
        srcs[pos] = ei[e];
        eids[pos] = e;
    }
}

// ---------------------------------------------------------------------------
// Fused attention gather: one wave per dst node; lane = head*32 + channel.
// Online softmax over the node's in-edges; h := leaky(h_skip + msg).
// ---------------------------------------------------------------------------
__global__ __launch_bounds__(256) void node_attn_k(
    const int* __restrict__ rowptr, const int* __restrict__ srcs,
    const int* __restrict__ eids, const float* __restrict__ ea,
    const float* __restrict__ q, const float* __restrict__ k,
    const float* __restrict__ v, const float* __restrict__ We,
    float* __restrict__ h)
{
    __shared__ float sWe[16 * 64];
    for (int i = threadIdx.x; i < 16 * 64; i += 256) sWe[i] = We[i];
    __syncthreads();

    int wave = threadIdx.x >> 6, lane = threadIdx.x & 63;
    int node = blockIdx.x * 4 + wave;
    if (node >= NN) return;

    int beg = rowptr[node], end = rowptr[node + 1];
    float qc = q[node * 64 + lane];

    float m = -1e30f, s = 0.f, acc = 0.f;
    for (int j = beg; j < end; ++j) {
        int src = srcs[j];
        int eid = eids[j];
        const float* ar = ea + (size_t)eid * 16;
        // edge projection for this lane's channel: broadcast 16 ea values via shfl
        float aval = ar[lane & 15];
        float ec = 0.f;
#pragma unroll
        for (int i = 0; i < 16; ++i)
            ec = fmaf(__shfl(aval, i, 16), sWe[i * 64 + lane], ec);
        float kc = k[src * 64 + lane] + ec;
        // per-head dot product: reduce q*k over the 32-lane half-wave
        float p = qc * kc;
#pragma unroll
        for (int off = 16; off >= 1; off >>= 1) p += __shfl_xor(p, off, 32);
        float alpha = p * 0.17677669529663687f;  // 1/sqrt(32)
        // online softmax update
        float mn = fmaxf(m, alpha);
        float scale = __expf(m - mn);
        float w = __expf(alpha - mn);
        s = s * scale + w;
        acc = acc * scale + w * (v[src * 64 + lane] + ec);
        m = mn;
    }
    float msg = (end > beg) ? acc / s : 0.f;
    int idx = node * 64 + lane;
    h[idx] = leaky(h[idx] + msg);
}

// ---------------------------------------------------------------------------
extern "C" void kernel_launch(void* const* d_in, const int* in_sizes, int n_in,
                              void* d_out, int out_size, void* d_ws, size_t ws_size,
                              hipStream_t stream)
{
    const float* x = (const float*)d_in[0];
    const int* ei = (const int*)d_in[2];
    const float* ea = (const float*)d_in[3];
    const float* Wq[2] = {(const float*)d_in[5], (const float*)d_in[14]};
    const float* bq[2] = {(const float*)d_in[6], (const float*)d_in[15]};
    const float* Wk[2] = {(const float*)d_in[7], (const float*)d_in[16]};
    const float* bk[2] = {(const float*)d_in[8], (const float*)d_in[17]};
    const float* Wv[2] = {(const float*)d_in[9], (const float*)d_in[18]};
    const float* bv[2] = {(const float*)d_in[10], (const float*)d_in[19]};
    const float* We[2] = {(const float*)d_in[11], (const float*)d_in[20]};
    const float* Ws[2] = {(const float*)d_in[12], (const float*)d_in[21]};
    const float* bs[2] = {(const float*)d_in[13], (const float*)d_in[22]};
    const float* Wm1 = (const float*)d_in[23];
    const float* bm1 = (const float*)d_in[24];
    const float* Wm2 = (const float*)d_in[25];
    const float* bm2 = (const float*)d_in[26];

    float* ws = (float*)d_ws;
    float* q = ws;                    // N*64
    float* k = q + NN * 64;           // N*64
    float* v = k + NN * 64;           // N*64
    float* h1 = v + NN * 64;          // N*64
    float* h2 = h1 + NN * 64;         // N*64
    int* deg = (int*)(h2 + NN * 64);  // NN
    int* rowptr = deg + NN;           // NN+1
    int* fill = rowptr + NN + 1;      // NN
    int* srcs = fill + NN;            // EE
    int* eids = srcs + EE;            // EE
    float* tmp = q;                   // N*32 — q is dead after layer 2

    int edge_grid = (EE + 255) / 256;
    int qkvs_grid = (NN + 31) / 32;
    int attn_grid = (NN + 3) / 4;

    // --- CSR build (once; graph shared by both layers) ---
    hipMemsetAsync(deg, 0, (size_t)NN * sizeof(int), stream);
    hist_k<<<edge_grid, 256, 0, stream>>>(ei, deg);
    scan_k<<<1, 1024, 0, stream>>>(deg, rowptr, fill);
    scatter_k<<<edge_grid, 256, 0, stream>>>(ei, fill, srcs, eids);

    const float* xin = x;
    float* hout[2] = {h1, h2};
    for (int L = 0; L < 2; ++L) {
        float* h = hout[L];
        qkvs_k<8><<<qkvs_grid, 256, 0, stream>>>(
            xin, Wq[L], bq[L], Wk[L], bk[L], Wv[L], bv[L], Ws[L], bs[L], q, k, v, h);
        node_attn_k<<<attn_grid, 256, 0, stream>>>(
            rowptr, srcs, eids, ea, q, k, v, We[L], h);
        xin = h;
    }
    linear_k<64, 32, 1><<<(NN * 32 + 255) / 256, 256, 0, stream>>>(h2, Wm1, bm1, tmp, NN);
    linear_k<32, 32, 0><<<(NN * 32 + 255) / 256, 256, 0, stream>>>(tmp, Wm2, bm2, (float*)d_out, NN);
}

// Round 16
// 756.046 us; speedup vs baseline: 8.0301x; 1.1371x over previous
//
#include <hip/hip_runtime.h>

#define NN 50000
#define EE 800000
#define SCB 1024
#define SCN ((NN + SCB - 1) / SCB)   // 49 scan tiles

__device__ __forceinline__ float leaky(float z) { return z >= 0.f ? z : 0.01f * z; }

// ---------------------------------------------------------------------------
// Fused node GEMM: q,k,v = x@W*+b*, h = x@Ws+bs (skip term; attn adds into it).
// ---------------------------------------------------------------------------
template <int ROWS>
__global__ __launch_bounds__(256) void qkvs_k(
    const float* __restrict__ X,
    const float* __restrict__ Wq, const float* __restrict__ bq,
    const float* __restrict__ Wk, const float* __restrict__ bk,
    const float* __restrict__ Wv, const float* __restrict__ bv,
    const float* __restrict__ Ws, const float* __restrict__ bs,
    float* __restrict__ q, float* __restrict__ k, float* __restrict__ v,
    float* __restrict__ h)
{
    constexpr int RPB = 4 * ROWS;
    __shared__ float sX[RPB * 64];
    int base = blockIdx.x * RPB;
    for (int i = threadIdx.x; i < RPB * 64; i += 256) {
        int r = base + (i >> 6);
        sX[i] = (r < NN) ? X[r * 64 + (i & 63)] : 0.f;
    }
    __syncthreads();
    int col = threadIdx.x & 63;
    int slot = threadIdx.x >> 6;
    float accq[ROWS], acck[ROWS], accv[ROWS], accs[ROWS];
#pragma unroll
    for (int r = 0; r < ROWS; ++r) {
        accq[r] = bq[col]; acck[r] = bk[col];
        accv[r] = bv[col]; accs[r] = bs[col];
    }
#pragma unroll 16
    for (int kk = 0; kk < 64; ++kk) {
        float wq = Wq[kk * 64 + col], wk = Wk[kk * 64 + col];
        float wv = Wv[kk * 64 + col], ws = Ws[kk * 64 + col];
#pragma unroll
        for (int r = 0; r < ROWS; ++r) {
            float xv = sX[(slot * ROWS + r) * 64 + kk];
            accq[r] = fmaf(xv, wq, accq[r]);
            acck[r] = fmaf(xv, wk, acck[r]);
            accv[r] = fmaf(xv, wv, accv[r]);
            accs[r] = fmaf(xv, ws, accs[r]);
        }
    }
#pragma unroll
    for (int r = 0; r < ROWS; ++r) {
        int row = base + slot * ROWS + r;
        if (row < NN) {
            q[row * 64 + col] = accq[r];
            k[row * 64 + col] = acck[r];
            v[row * 64 + col] = accv[r];
            h[row * 64 + col] = accs[r];
        }
    }
}

// ---------------------------------------------------------------------------
// MLP linear
// ---------------------------------------------------------------------------
template <int FI, int FO, int ACT>
__global__ void linear_k(const float* __restrict__ X, const float* __restrict__ W,
                         const float* __restrict__ b, float* __restrict__ Y, int n)
{
    int idx = blockIdx.x * blockDim.x + threadIdx.x;
    if (idx >= n * FO) return;
    int col = idx % FO, row = idx / FO;
    float acc = b[col];
    const float* xr = X + row * FI;
#pragma unroll
    for (int kk = 0; kk < FI; ++kk) acc = fmaf(xr[kk], W[kk * FO + col], acc);
    if (ACT) acc = leaky(acc);
    Y[idx] = acc;
}

// ---------------------------------------------------------------------------
// CSR build: hist -> 3-kernel parallel scan -> scatter (int2-packed adjacency)
// ---------------------------------------------------------------------------
__global__ void hist_k(const int* __restrict__ ei, int* __restrict__ deg)
{
    int e = blockIdx.x * 256 + threadIdx.x;
    if (e < EE) atomicAdd(&deg[ei[EE + e]], 1);
}

// per-tile inclusive scan; rowptr[i+1] = tile-local inclusive, partials[b] = tile sum
__global__ __launch_bounds__(SCB) void scan1_k(const int* __restrict__ deg,
                                               int* __restrict__ rowptr,
                                               int* __restrict__ partials)
{
    __shared__ int sbuf[SCB];
    int b = blockIdx.x, tid = threadIdx.x, i = b * SCB + tid;
    int x = (i < NN) ? deg[i] : 0;
    sbuf[tid] = x;
    __syncthreads();
    for (int off = 1; off < SCB; off <<= 1) {
        int t = (tid >= off) ? sbuf[tid - off] : 0;
        __syncthreads();
        sbuf[tid] += t;
        __syncthreads();
    }
    if (i < NN) rowptr[i + 1] = sbuf[tid];
    if (tid == SCB - 1) partials[b] = sbuf[tid];
}

// single-wave exclusive scan of the SCN (<=64) tile sums, in place
__global__ __launch_bounds__(64) void scan2_k(int* __restrict__ partials)
{
    int tid = threadIdx.x;
    int val = (tid < SCN) ? partials[tid] : 0;
    int incl = val;
#pragma unroll
    for (int off = 1; off < 64; off <<= 1) {
        int t = __shfl_up(incl, off, 64);
        if (tid >= off) incl += t;
    }
    if (tid < SCN) partials[tid] = incl - val;   // exclusive prefix
}

// add tile offset; fill[i] = exclusive prefix (write cursor); rowptr[0] = 0
__global__ __launch_bounds__(SCB) void scan3_k(const int* __restrict__ deg,
                                               int* __restrict__ rowptr,
                                               const int* __restrict__ partials,
                                               int* __restrict__ fill)
{
    int b = blockIdx.x, tid = threadIdx.x, i = b * SCB + tid;
    if (i < NN) {
        int rp = rowptr[i + 1] + partials[b];
        rowptr[i + 1] = rp;
        fill[i] = rp - deg[i];
    }
    if (i == 0) rowptr[0] = 0;
}

__global__ void scatter_k(const int* __restrict__ ei, int* __restrict__ fill,
                          int2* __restrict__ adj)
{
    int e = blockIdx.x * 256 + threadIdx.x;
    if (e < EE) {
        int dst = ei[EE + e];
        int pos = atomicAdd(&fill[dst], 1);
        adj[pos] = make_int2(ei[e], e);   // (src, edge id) in one 8B slot
    }
}

// ---------------------------------------------------------------------------
// Fused attention gather: one wave per dst node; lane = head*32 + channel.
// Online softmax; edge loop software-pipelined (prefetch j+1 during compute j).
// ---------------------------------------------------------------------------
__global__ __launch_bounds__(256) void node_attn_k(
    const int* __restrict__ rowptr, const int2* __restrict__ adj,
    const float* __restrict__ ea,
    const float* __restrict__ q, const float* __restrict__ k,
    const float* __restrict__ v, const float* __restrict__ We,
    float* __restrict__ h)
{
    __shared__ float sWe[16 * 64];
    for (int i = threadIdx.x; i < 16 * 64; i += 256) sWe[i] = We[i];
    __syncthreads();

    int wave = threadIdx.x >> 6, lane = threadIdx.x & 63;
    int node = blockIdx.x * 4 + wave;
    if (node >= NN) return;

    // wave-uniform loop bounds -> SGPR (enables scalar loads of adj)
    int beg = __builtin_amdgcn_readfirstlane(rowptr[node]);
    int end = __builtin_amdgcn_readfirstlane(rowptr[node + 1]);
    float qc = q[node * 64 + lane];

    float m = -1e30f, s = 0.f, acc = 0.f;
    if (beg < end) {
        int2 a0 = adj[beg];
        float kc = k[(size_t)a0.x * 64 + lane];
        float vc = v[(size_t)a0.x * 64 + lane];
        float av = ea[(size_t)a0.y * 16 + (lane & 15)];
        for (int j = beg; j < end; ++j) {
            // issue next edge's loads before consuming current edge's data
            int jn = (j + 1 < end) ? j + 1 : j;
            int2 a1 = adj[jn];
            float kcn = k[(size_t)a1.x * 64 + lane];
            float vcn = v[(size_t)a1.x * 64 + lane];
            float avn = ea[(size_t)a1.y * 16 + (lane & 15)];

            // edge projection: ec = (ea[e] @ We)[lane]; 2 chains to halve dep latency
            float ec0 = 0.f, ec1 = 0.f;
#pragma unroll
            for (int i = 0; i < 16; i += 2) {
                ec0 = fmaf(__shfl(av, i, 16),     sWe[i * 64 + lane],       ec0);
                ec1 = fmaf(__shfl(av, i + 1, 16), sWe[(i + 1) * 64 + lane], ec1);
            }
            float ec = ec0 + ec1;
            // per-head dot over the 32-lane half-wave
            float p = qc * (kc + ec);
#pragma unroll
            for (int off = 16; off >= 1; off >>= 1) p += __shfl_xor(p, off, 32);
            float alpha = p * 0.17677669529663687f;   // 1/sqrt(32)
            // online softmax
            float mn = fmaxf(m, alpha);
            float sc = __expf(m - mn);
            float w  = __expf(alpha - mn);
            s   = s * sc + w;
            acc = acc * sc + w * (vc + ec);
            m = mn;
            kc = kcn; vc = vcn; av = avn;
        }
        acc = acc / s;
    }
    int idx = node * 64 + lane;
    h[idx] = leaky(h[idx] + acc);
}

// ---------------------------------------------------------------------------
extern "C" void kernel_launch(void* const* d_in, const int* in_sizes, int n_in,
                              void* d_out, int out_size, void* d_ws, size_t ws_size,
                              hipStream_t stream)
{
    const float* x = (const float*)d_in[0];
    const int* ei = (const int*)d_in[2];
    const float* ea = (const float*)d_in[3];
    const float* Wq[2] = {(const float*)d_in[5], (const float*)d_in[14]};
    const float* bq[2] = {(const float*)d_in[6], (const float*)d_in[15]};
    const float* Wk[2] = {(const float*)d_in[7], (const float*)d_in[16]};
    const float* bk[2] = {(const float*)d_in[8], (const float*)d_in[17]};
    const float* Wv[2] = {(const float*)d_in[9], (const float*)d_in[18]};
    const float* bv[2] = {(const float*)d_in[10], (const float*)d_in[19]};
    const float* We[2] = {(const float*)d_in[11], (const float*)d_in[20]};
    const float* Ws[2] = {(const float*)d_in[12], (const float*)d_in[21]};
    const float* bs[2] = {(const float*)d_in[13], (const float*)d_in[22]};
    const float* Wm1 = (const float*)d_in[23];
    const float* bm1 = (const float*)d_in[24];
    const float* Wm2 = (const float*)d_in[25];
    const float* bm2 = (const float*)d_in[26];

    float* ws = (float*)d_ws;
    float* q = ws;                    // N*64
    float* k = q + NN * 64;           // N*64
    float* v = k + NN * 64;           // N*64
    float* h1 = v + NN * 64;          // N*64
    float* h2 = h1 + NN * 64;         // N*64
    int* deg = (int*)(h2 + NN * 64);  // NN
    int* rowptr = deg + NN;           // NN+1
    int* fill = rowptr + NN + 1;      // NN
    int* partials = fill + NN;        // 64 scan tile sums + 1 pad
    // +65 (not +64): keeps the running int count EVEN -> adj is 8-byte aligned
    int2* adj = (int2*)(partials + 65);              // EE int2
    float* tmp = q;                   // N*32 — q is dead after layer-2 attn

    int edge_grid = (EE + 255) / 256;
    int qkvs_grid = (NN + 31) / 32;
    int attn_grid = (NN + 3) / 4;

    // --- CSR build (once; graph shared by both layers) ---
    hipMemsetAsync(deg, 0, (size_t)NN * sizeof(int), stream);
    hist_k<<<edge_grid, 256, 0, stream>>>(ei, deg);
    scan1_k<<<SCN, SCB, 0, stream>>>(deg, rowptr, partials);
    scan2_k<<<1, 64, 0, stream>>>(partials);
    scan3_k<<<SCN, SCB, 0, stream>>>(deg, rowptr, partials, fill);
    scatter_k<<<edge_grid, 256, 0, stream>>>(ei, fill, adj);

    const float* xin = x;
    float* hout[2] = {h1, h2};
    for (int L = 0; L < 2; ++L) {
        float* h = hout[L];
        qkvs_k<8><<<qkvs_grid, 256, 0, stream>>>(
            xin, Wq[L], bq[L], Wk[L], bk[L], Wv[L], bv[L], Ws[L], bs[L], q, k, v, h);
        node_attn_k<<<attn_grid, 256, 0, stream>>>(
            rowptr, adj, ea, q, k, v, We[L], h);
        xin = h;
    }
    linear_k<64, 32, 1><<<(NN * 32 + 255) / 256, 256, 0, stream>>>(h2, Wm1, bm1, tmp, NN);
    linear_k<32, 32, 0><<<(NN * 32 + 255) / 256, 256, 0, stream>>>(tmp, Wm2, bm2, (float*)d_out, NN);
}

// Round 17
// 585.684 us; speedup vs baseline: 10.3658x; 1.2909x over previous
//
#include <hip/hip_runtime.h>

#define NN 50000
#define EE 800000
#define SCB 1024
#define SCN ((NN + SCB - 1) / SCB)   // 49 scan tiles

__device__ __forceinline__ float leaky(float z) { return z >= 0.f ? z : 0.01f * z; }

// DPP-based butterfly add step (VALU pipe, not LDS)
template <int CTRL>
__device__ __forceinline__ float dpp_add(float x)
{
    int t = __builtin_amdgcn_update_dpp(0, __float_as_int(x), CTRL, 0xF, 0xF, true);
    return x + __int_as_float(t);
}

// ---------------------------------------------------------------------------
// Fused node GEMM: q,k,v = x@W*+b*, h = x@Ws+bs (skip term; attn adds into it).
// ---------------------------------------------------------------------------
template <int ROWS>
__global__ __launch_bounds__(256) void qkvs_k(
    const float* __restrict__ X,
    const float* __restrict__ Wq, const float* __restrict__ bq,
    const float* __restrict__ Wk, const float* __restrict__ bk,
    const float* __restrict__ Wv, const float* __restrict__ bv,
    const float* __restrict__ Ws, const float* __restrict__ bs,
    float* __restrict__ q, float* __restrict__ k, float* __restrict__ v,
    float* __restrict__ h)
{
    constexpr int RPB = 4 * ROWS;
    __shared__ float sX[RPB * 64];
    int base = blockIdx.x * RPB;
    for (int i = threadIdx.x; i < RPB * 64; i += 256) {
        int r = base + (i >> 6);
        sX[i] = (r < NN) ? X[r * 64 + (i & 63)] : 0.f;
    }
    __syncthreads();
    int col = threadIdx.x & 63;
    int slot = threadIdx.x >> 6;
    float accq[ROWS], acck[ROWS], accv[ROWS], accs[ROWS];
#pragma unroll
    for (int r = 0; r < ROWS; ++r) {
        accq[r] = bq[col]; acck[r] = bk[col];
        accv[r] = bv[col]; accs[r] = bs[col];
    }
#pragma unroll 16
    for (int kk = 0; kk < 64; ++kk) {
        float wq = Wq[kk * 64 + col], wk = Wk[kk * 64 + col];
        float wv = Wv[kk * 64 + col], ws = Ws[kk * 64 + col];
#pragma unroll
        for (int r = 0; r < ROWS; ++r) {
            float xv = sX[(slot * ROWS + r) * 64 + kk];
            accq[r] = fmaf(xv, wq, accq[r]);
            acck[r] = fmaf(xv, wk, acck[r]);
            accv[r] = fmaf(xv, wv, accv[r]);
            accs[r] = fmaf(xv, ws, accs[r]);
        }
    }
#pragma unroll
    for (int r = 0; r < ROWS; ++r) {
        int row = base + slot * ROWS + r;
        if (row < NN) {
            q[row * 64 + col] = accq[r];
            k[row * 64 + col] = acck[r];
            v[row * 64 + col] = accv[r];
            h[row * 64 + col] = accs[r];
        }
    }
}

// ---------------------------------------------------------------------------
// MLP linear
// ---------------------------------------------------------------------------
template <int FI, int FO, int ACT>
__global__ void linear_k(const float* __restrict__ X, const float* __restrict__ W,
                         const float* __restrict__ b, float* __restrict__ Y, int n)
{
    int idx = blockIdx.x * blockDim.x + threadIdx.x;
    if (idx >= n * FO) return;
    int col = idx % FO, row = idx / FO;
    float acc = b[col];
    const float* xr = X + row * FI;
#pragma unroll
    for (int kk = 0; kk < FI; ++kk) acc = fmaf(xr[kk], W[kk * FO + col], acc);
    if (ACT) acc = leaky(acc);
    Y[idx] = acc;
}

// ---------------------------------------------------------------------------
// CSR build: hist -> 3-kernel parallel scan -> scatter (int2-packed adjacency)
// ---------------------------------------------------------------------------
__global__ void hist_k(const int* __restrict__ ei, int* __restrict__ deg)
{
    int e = blockIdx.x * 256 + threadIdx.x;
    if (e < EE) atomicAdd(&deg[ei[EE + e]], 1);
}

__global__ __launch_bounds__(SCB) void scan1_k(const int* __restrict__ deg,
                                               int* __restrict__ rowptr,
                                               int* __restrict__ partials)
{
    __shared__ int sbuf[SCB];
    int b = blockIdx.x, tid = threadIdx.x, i = b * SCB + tid;
    int x = (i < NN) ? deg[i] : 0;
    sbuf[tid] = x;
    __syncthreads();
    for (int off = 1; off < SCB; off <<= 1) {
        int t = (tid >= off) ? sbuf[tid - off] : 0;
        __syncthreads();
        sbuf[tid] += t;
        __syncthreads();
    }
    if (i < NN) rowptr[i + 1] = sbuf[tid];
    if (tid == SCB - 1) partials[b] = sbuf[tid];
}

__global__ __launch_bounds__(64) void scan2_k(int* __restrict__ partials)
{
    int tid = threadIdx.x;
    int val = (tid < SCN) ? partials[tid] : 0;
    int incl = val;
#pragma unroll
    for (int off = 1; off < 64; off <<= 1) {
        int t = __shfl_up(incl, off, 64);
        if (tid >= off) incl += t;
    }
    if (tid < SCN) partials[tid] = incl - val;   // exclusive prefix
}

__global__ __launch_bounds__(SCB) void scan3_k(const int* __restrict__ deg,
                                               int* __restrict__ rowptr,
                                               const int* __restrict__ partials,
                                               int* __restrict__ fill)
{
    int b = blockIdx.x, tid = threadIdx.x, i = b * SCB + tid;
    if (i < NN) {
        int rp = rowptr[i + 1] + partials[b];
        rowptr[i + 1] = rp;
        fill[i] = rp - deg[i];
    }
    if (i == 0) rowptr[0] = 0;
}

__global__ void scatter_k(const int* __restrict__ ei, int* __restrict__ fill,
                          int2* __restrict__ adj)
{
    int e = blockIdx.x * 256 + threadIdx.x;
    if (e < EE) {
        int dst = ei[EE + e];
        int pos = atomicAdd(&fill[dst], 1);
        adj[pos] = make_int2(ei[e], e);   // (src, edge id) in one 8B slot
    }
}

// ---------------------------------------------------------------------------
// Fused attention gather: one wave per dst node; lane = head*32 + channel.
// LDS-pipe-minimal: ea via SGPR (wave-uniform), We hoisted to registers,
// reduce = 4 DPP steps + 1 ds_swizzle (xor16). Online softmax.
// ---------------------------------------------------------------------------
__global__ __launch_bounds__(256) void node_attn_k(
    const int* __restrict__ rowptr, const int2* __restrict__ adj,
    const float* __restrict__ ea,
    const float* __restrict__ q, const float* __restrict__ k,
    const float* __restrict__ v, const float* __restrict__ We,
    float* __restrict__ h)
{
    int wave = threadIdx.x >> 6, lane = threadIdx.x & 63;
    int node = blockIdx.x * 4 + wave;
    if (node >= NN) return;

    // edge-invariant We column for this lane -> registers (L2-hot, coalesced)
    float we[16];
#pragma unroll
    for (int i = 0; i < 16; ++i) we[i] = We[i * 64 + lane];

    int beg = __builtin_amdgcn_readfirstlane(rowptr[node]);
    int end = __builtin_amdgcn_readfirstlane(rowptr[node + 1]);
    float qc = q[node * 64 + lane];

    float m = -1e30f, s = 0.f, acc = 0.f;
    if (beg < end) {
        int2 a0 = adj[beg];
        int src = __builtin_amdgcn_readfirstlane(a0.x);
        int eid = __builtin_amdgcn_readfirstlane(a0.y);
        float kc = k[(size_t)src * 64 + lane];
        float vc = v[(size_t)src * 64 + lane];
        float eav[16];
#pragma unroll
        for (int i = 0; i < 16; ++i) eav[i] = ea[(size_t)eid * 16 + i];  // SGPR loads

        for (int j = beg; j < end; ++j) {
            // prefetch next edge (wave-uniform scalars + per-lane k/v rows)
            int jn = (j + 1 < end) ? j + 1 : j;
            int2 a1 = adj[jn];
            int srcn = __builtin_amdgcn_readfirstlane(a1.x);
            int eidn = __builtin_amdgcn_readfirstlane(a1.y);
            float kcn = k[(size_t)srcn * 64 + lane];
            float vcn = v[(size_t)srcn * 64 + lane];
            float ean[16];
#pragma unroll
            for (int i = 0; i < 16; ++i) ean[i] = ea[(size_t)eidn * 16 + i];

            // ec = (ea[e] @ We)[lane]: SGPR x VGPR FMAs, 4 chains
            float ec0 = 0.f, ec1 = 0.f, ec2 = 0.f, ec3 = 0.f;
#pragma unroll
            for (int i = 0; i < 16; i += 4) {
                ec0 = fmaf(eav[i],     we[i],     ec0);
                ec1 = fmaf(eav[i + 1], we[i + 1], ec1);
                ec2 = fmaf(eav[i + 2], we[i + 2], ec2);
                ec3 = fmaf(eav[i + 3], we[i + 3], ec3);
            }
            float ec = (ec0 + ec1) + (ec2 + ec3);

            // per-head dot over 32-lane half: 4 DPP adds + 1 ds_swizzle (xor16)
            float p = qc * (kc + ec);
            p = dpp_add<0xB1>(p);    // quad_perm(1,0,3,2): xor1
            p = dpp_add<0x4E>(p);    // quad_perm(2,3,0,1): xor2
            p = dpp_add<0x141>(p);   // row_half_mirror (values quad-uniform)
            p = dpp_add<0x140>(p);   // row_mirror (values half-uniform)
            p += __int_as_float(__builtin_amdgcn_ds_swizzle(__float_as_int(p), 0x401F)); // xor16

            float alpha = p * 0.17677669529663687f;   // 1/sqrt(32)
            float mn = fmaxf(m, alpha);
            float sc = __expf(m - mn);
            float w  = __expf(alpha - mn);
            s   = s * sc + w;
            acc = acc * sc + w * (vc + ec);
            m = mn;
            kc = kcn; vc = vcn;
#pragma unroll
            for (int i = 0; i < 16; ++i) eav[i] = ean[i];
        }
        acc = acc / s;
    }
    int idx = node * 64 + lane;
    h[idx] = leaky(h[idx] + acc);
}

// ---------------------------------------------------------------------------
extern "C" void kernel_launch(void* const* d_in, const int* in_sizes, int n_in,
                              void* d_out, int out_size, void* d_ws, size_t ws_size,
                              hipStream_t stream)
{
    const float* x = (const float*)d_in[0];
    const int* ei = (const int*)d_in[2];
    const float* ea = (const float*)d_in[3];
    const float* Wq[2] = {(const float*)d_in[5], (const float*)d_in[14]};
    const float* bq[2] = {(const float*)d_in[6], (const float*)d_in[15]};
    const float* Wk[2] = {(const float*)d_in[7], (const float*)d_in[16]};
    const float* bk[2] = {(const float*)d_in[8], (const float*)d_in[17]};
    const float* Wv[2] = {(const float*)d_in[9], (const float*)d_in[18]};
    const float* bv[2] = {(const float*)d_in[10], (const float*)d_in[19]};
    const float* We[2] = {(const float*)d_in[11], (const float*)d_in[20]};
    const float* Ws[2] = {(const float*)d_in[12], (const float*)d_in[21]};
    const float* bs[2] = {(const float*)d_in[13], (const float*)d_in[22]};
    const float* Wm1 = (const float*)d_in[23];
    const float* bm1 = (const float*)d_in[24];
    const float* Wm2 = (const float*)d_in[25];
    const float* bm2 = (const float*)d_in[26];

    float* ws = (float*)d_ws;
    float* q = ws;                    // N*64
    float* k = q + NN * 64;           // N*64
    float* v = k + NN * 64;           // N*64
    float* h1 = v + NN * 64;          // N*64
    float* h2 = h1 + NN * 64;         // N*64
    int* deg = (int*)(h2 + NN * 64);  // NN
    int* rowptr = deg + NN;           // NN+1
    int* fill = rowptr + NN + 1;      // NN
    int* partials = fill + NN;        // 64 scan tile sums + 1 pad
    // +65 (not +64): keeps the running int count EVEN -> adj is 8-byte aligned
    int2* adj = (int2*)(partials + 65);              // EE int2
    float* tmp = q;                   // N*32 — q is dead after layer-2 attn

    int edge_grid = (EE + 255) / 256;
    int qkvs_grid = (NN + 31) / 32;
    int attn_grid = (NN + 3) / 4;

    // --- CSR build (once; graph shared by both layers) ---
    hipMemsetAsync(deg, 0, (size_t)NN * sizeof(int), stream);
    hist_k<<<edge_grid, 256, 0, stream>>>(ei, deg);
    scan1_k<<<SCN, SCB, 0, stream>>>(deg, rowptr, partials);
    scan2_k<<<1, 64, 0, stream>>>(partials);
    scan3_k<<<SCN, SCB, 0, stream>>>(deg, rowptr, partials, fill);
    scatter_k<<<edge_grid, 256, 0, stream>>>(ei, fill, adj);

    const float* xin = x;
    float* hout[2] = {h1, h2};
    for (int L = 0; L < 2; ++L) {
        float* h = hout[L];
        qkvs_k<8><<<qkvs_grid, 256, 0, stream>>>(
            xin, Wq[L], bq[L], Wk[L], bk[L], Wv[L], bv[L], Ws[L], bs[L], q, k, v, h);
        node_attn_k<<<attn_grid, 256, 0, stream>>>(
            rowptr, adj, ea, q, k, v, We[L], h);
        xin = h;
    }
    linear_k<64, 32, 1><<<(NN * 32 + 255) / 256, 256, 0, stream>>>(h2, Wm1, bm1, tmp, NN);
    linear_k<32, 32, 0><<<(NN * 32 + 255) / 256, 256, 0, stream>>>(tmp, Wm2, bm2, (float*)d_out, NN);
}